// Round 1
// baseline (941.678 us; speedup 1.0000x reference)
//
#include <hip/hip_runtime.h>
#include <stdint.h>

#define NROW 4096
#define NDIM 512
#define THRS 0.05f

// ---------------- workspace layout ----------------
#define XN_OFF   0ull
#define XN_SZ    (3ull*4096ull*512ull*4ull)        // 25165824
#define S2_OFF   (XN_OFF + XN_SZ)
#define S2_SZ    (3ull*4096ull*4ull)
#define RS_OFF   (S2_OFF + S2_SZ)
#define RS_SZ    (3ull*4096ull*4ull)
#define G_OFF    (RS_OFF + RS_SZ)                  // 25264128 (256-aligned)
#define G_SZ     (3ull*4096ull*4096ull*4ull)       // 201326592
#define ACC_OFF  (G_OFF + G_SZ)
#define WS_NEEDED (ACC_OFF + 64ull)

// ---------------- Threefry-2x32 (JAX-exact) ----------------
__host__ __device__ __forceinline__ void tf2x32(uint32_t k0, uint32_t k1,
                                                uint32_t x0, uint32_t x1,
                                                uint32_t* o0, uint32_t* o1) {
  uint32_t ks2 = k0 ^ k1 ^ 0x1BD11BDAu;
  x0 += k0; x1 += k1;
#define TFR(r) { x0 += x1; x1 = (x1 << (r)) | (x1 >> (32 - (r))); x1 ^= x0; }
  TFR(13) TFR(15) TFR(26) TFR(6)
  x0 += k1; x1 += ks2 + 1u;
  TFR(17) TFR(29) TFR(16) TFR(24)
  x0 += ks2; x1 += k0 + 2u;
  TFR(13) TFR(15) TFR(26) TFR(6)
  x0 += k0; x1 += k1 + 3u;
  TFR(17) TFR(29) TFR(16) TFR(24)
  x0 += k1; x1 += ks2 + 4u;
  TFR(13) TFR(15) TFR(26) TFR(6)
  x0 += ks2; x1 += k0 + 5u;
#undef TFR
  *o0 = x0; *o1 = x1;
}

struct Keys { uint32_t k[6]; };

// ---------------- normalize: one block per row ----------------
__global__ __launch_bounds__(128) void norm_kernel(const float* __restrict__ X,
                                                   float* __restrict__ Xn,
                                                   float* __restrict__ s2,
                                                   float* __restrict__ rs) {
  const int row = blockIdx.x;
  const int tid = threadIdx.x;
  const int lane = tid & 63, wid = tid >> 6;
  const float4 v = *(const float4*)(X + (size_t)row * NDIM + tid * 4);
  float ss = v.x*v.x + v.y*v.y + v.z*v.z + v.w*v.w;
  #pragma unroll
  for (int off = 32; off; off >>= 1) ss += __shfl_down(ss, off);
  __shared__ float sw[2];
  if (lane == 0) sw[wid] = ss;
  __syncthreads();
  const float tot = sw[0] + sw[1];
  const float den = fmaxf(sqrtf(tot), 1e-12f);
  float4 n4;
  n4.x = v.x / den; n4.y = v.y / den; n4.z = v.z / den; n4.w = v.w / den;
  *(float4*)(Xn + (size_t)row * NDIM + tid * 4) = n4;
  float ps = n4.x + n4.y + n4.z + n4.w;
  float p2 = n4.x*n4.x + n4.y*n4.y + n4.z*n4.z + n4.w*n4.w;
  #pragma unroll
  for (int off = 32; off; off >>= 1) { ps += __shfl_down(ps, off); p2 += __shfl_down(p2, off); }
  __shared__ float sw2[4];
  if (lane == 0) { sw2[wid] = ps; sw2[2 + wid] = p2; }
  __syncthreads();
  if (tid == 0) { rs[row] = sw2[0] + sw2[1]; s2[row] = sw2[2] + sw2[3]; }
}

// ---------------- fp32 SYRK-style GEMM: C = A * A^T (full grid) ----------------
#define GBK 32
__global__ __launch_bounds__(256) void gemm_aat(const float* __restrict__ A,
                                                float* __restrict__ C) {
  __shared__ float As[GBK][128];
  __shared__ float Bs[GBK][128];
  const int bi = blockIdx.y, bj = blockIdx.x;
  const int tid = threadIdx.x;
  const int tx = tid & 15, ty = tid >> 4;
  float acc[8][8];
  #pragma unroll
  for (int e = 0; e < 8; ++e)
    #pragma unroll
    for (int f = 0; f < 8; ++f) acc[e][f] = 0.0f;

  const float* __restrict__ Arow = A + (size_t)bi * 128 * NDIM;
  const float* __restrict__ Brow = A + (size_t)bj * 128 * NDIM;

  for (int kt = 0; kt < NDIM; kt += GBK) {
    #pragma unroll
    for (int p = 0; p < 4; ++p) {
      const int q = p * 256 + tid;       // 1024 float4 per tile
      const int row = q >> 3;            // 8 float4 per row
      const int k4 = (q & 7) * 4;
      float4 av = *(const float4*)(Arow + (size_t)row * NDIM + kt + k4);
      As[k4 + 0][row] = av.x; As[k4 + 1][row] = av.y;
      As[k4 + 2][row] = av.z; As[k4 + 3][row] = av.w;
      float4 bv = *(const float4*)(Brow + (size_t)row * NDIM + kt + k4);
      Bs[k4 + 0][row] = bv.x; Bs[k4 + 1][row] = bv.y;
      Bs[k4 + 2][row] = bv.z; Bs[k4 + 3][row] = bv.w;
    }
    __syncthreads();
    #pragma unroll
    for (int k = 0; k < GBK; ++k) {
      float a[8], b[8];
      *(float4*)&a[0] = *(const float4*)&As[k][ty * 8];
      *(float4*)&a[4] = *(const float4*)&As[k][ty * 8 + 4];
      *(float4*)&b[0] = *(const float4*)&Bs[k][tx * 8];
      *(float4*)&b[4] = *(const float4*)&Bs[k][tx * 8 + 4];
      #pragma unroll
      for (int e = 0; e < 8; ++e)
        #pragma unroll
        for (int f = 0; f < 8; ++f) acc[e][f] = fmaf(a[e], b[f], acc[e][f]);
    }
    __syncthreads();
  }
  float* Cp = C + (size_t)(bi * 128 + ty * 8) * NROW + bj * 128 + tx * 8;
  #pragma unroll
  for (int e = 0; e < 8; ++e) {
    *(float4*)(Cp + (size_t)e * NROW)     = *(float4*)&acc[e][0];
    *(float4*)(Cp + (size_t)e * NROW + 4) = *(float4*)&acc[e][4];
  }
}

// ---------------- fused mask/scan/sample/loss: one block per row ----------------
__global__ __launch_bounds__(256) void loss_kernel(const float* __restrict__ G,
                                                   const float* __restrict__ s2,
                                                   const float* __restrict__ rs,
                                                   double* __restrict__ lossAcc,
                                                   unsigned long long* __restrict__ posAcc,
                                                   Keys keys) {
  __shared__ float sRow[3][NROW];          // 48 KB
  __shared__ unsigned short zlist[NROW];   // 8 KB
  __shared__ int sWaveTot[4];
  __shared__ float sLoss[4];

  const int i = blockIdx.x;
  const int tid = threadIdx.x;
  const int lane = tid & 63, wid = tid >> 6;
  const int j0 = tid * 16;

  // stage the three G rows
  #pragma unroll
  for (int v = 0; v < 3; ++v) {
    const float* g = G + ((size_t)v << 24) + ((size_t)i << 12);
    #pragma unroll
    for (int p = 0; p < 4; ++p) {
      const int idx = p * 256 + tid;
      *(float4*)&sRow[v][idx * 4] = *(const float4*)(g + (size_t)idx * 4);
    }
  }
  __syncthreads();

  // masks: pos = U && j!=i ; zero = !pos (A is 0/1 with zero diagonal)
  uint32_t posm = 0;
  #pragma unroll
  for (int e = 0; e < 16; ++e) {
    const int j = j0 + e;
    const bool U = (sRow[0][j] > THRS) | (sRow[1][j] > THRS) | (sRow[2][j] > THRS);
    if (U && (j != i)) posm |= (1u << e);
  }

  // block scan of zero counts -> zlist (ordered zero positions)
  const int c = 16 - __popc(posm);
  int inc = c;
  #pragma unroll
  for (int off = 1; off < 64; off <<= 1) {
    const int t = __shfl_up(inc, off);
    if (lane >= off) inc += t;
  }
  if (lane == 63) sWaveTot[wid] = inc;
  __syncthreads();
  int base = inc - c;
  for (int w = 0; w < wid; ++w) base += sWaveTot[w];
  const int cnt = sWaveTot[0] + sWaveTot[1] + sWaveTot[2] + sWaveTot[3];
  int rank = base;
  #pragma unroll
  for (int e = 0; e < 16; ++e) {
    if (!((posm >> e) & 1)) zlist[rank++] = (unsigned short)(j0 + e);
  }
  __syncthreads();

  const float cntf = (float)cnt;
  const int cm1 = cnt - 1;
  float lossSum = 0.0f;

  #pragma unroll
  for (int v = 0; v < 3; ++v) {
    const float* s2v = s2 + v * NROW;
    const float* rsv = rs + v * NROW;
    const float s2i = s2v[i], rsi = rsv[i];
    const float rowA = s2i + 2e-6f * rsi + 5.12e-10f;   // d*eps^2 = 512e-12
    // transform S row -> D row in place
    #pragma unroll 4
    for (int e = 0; e < 16; ++e) {
      const int j = j0 + e;
      const float g = sRow[v][j];
      const float d2 = rowA + (s2v[j] - 2e-6f * rsv[j]) - 2.0f * g;
      sRow[v][j] = sqrtf(fmaxf(d2, 0.0f));
    }
    __syncthreads();

    const uint32_t fk0 = keys.k[2 * v], fk1 = keys.k[2 * v + 1];
    const uint32_t tbase = (uint32_t)i * 4096u + (uint32_t)j0;
    for (int e = 0; e < 16; ++e) {
      if ((posm >> e) & 1) {
        const uint32_t t = tbase + e;
        uint32_t y0, y1, bits;
        if (i < 2048) { tf2x32(fk0, fk1, t, t + 8388608u, &y0, &y1); bits = y0; }
        else          { tf2x32(fk0, fk1, t - 8388608u, t, &y0, &y1); bits = y1; }
        const float u = __uint_as_float((bits >> 9) | 0x3F800000u) - 1.0f;
        int r = (int)(u * cntf);
        r = min(r, cm1);
        const int n = zlist[r];
        const float dan = sRow[v][n];
        const float dij = sRow[v][j0 + e];
        lossSum += fmaxf(dij - dan + 1.0f, 0.0f);
      }
    }
    __syncthreads();  // protect sRow[v] reads before (nothing) & keep views in lockstep
  }

  // block reduce loss
  #pragma unroll
  for (int off = 32; off; off >>= 1) lossSum += __shfl_down(lossSum, off);
  if (lane == 0) sLoss[wid] = lossSum;
  __syncthreads();
  if (tid == 0) {
    const double tot = (double)sLoss[0] + (double)sLoss[1] + (double)sLoss[2] + (double)sLoss[3];
    atomicAdd(lossAcc, tot);
    atomicAdd(posAcc, (unsigned long long)(NROW - cnt));
  }
}

__global__ void finalize_kernel(const double* __restrict__ lossAcc,
                                const unsigned long long* __restrict__ posAcc,
                                float* __restrict__ out) {
  if (threadIdx.x == 0 && blockIdx.x == 0) {
    out[0] = (float)(lossAcc[0] / (double)posAcc[0]);
  }
}

// ---------------- launch ----------------
extern "C" void kernel_launch(void* const* d_in, const int* in_sizes, int n_in,
                              void* d_out, int out_size, void* d_ws, size_t ws_size,
                              hipStream_t stream) {
  if (ws_size < WS_NEEDED) return;  // workspace too small: leave poison as failure signal

  const float* Xs[3] = { (const float*)d_in[0], (const float*)d_in[1], (const float*)d_in[2] };
  char* ws = (char*)d_ws;
  float* Xn = (float*)(ws + XN_OFF);
  float* s2 = (float*)(ws + S2_OFF);
  float* rs = (float*)(ws + RS_OFF);
  float* G  = (float*)(ws + G_OFF);
  double* lossAcc = (double*)(ws + ACC_OFF);
  unsigned long long* posAcc = (unsigned long long*)(ws + ACC_OFF + 8);
  float* out = (float*)d_out;

  hipMemsetAsync(ws + ACC_OFF, 0, 16, stream);

  for (int v = 0; v < 3; ++v)
    norm_kernel<<<NROW, 128, 0, stream>>>(Xs[v], Xn + (size_t)v * NROW * NDIM,
                                          s2 + v * NROW, rs + v * NROW);

  for (int v = 0; v < 3; ++v)
    gemm_aat<<<dim3(32, 32), 256, 0, stream>>>(Xn + (size_t)v * NROW * NDIM,
                                               G + ((size_t)v << 24));

  // host-side JAX key derivation: key(42) = (0,42); fold_in(key, v) = threefry((0,42),(0,v))
  Keys keys;
  for (uint32_t v = 0; v < 3; ++v) {
    uint32_t y0, y1;
    tf2x32(0u, 42u, 0u, v, &y0, &y1);
    keys.k[2 * v] = y0; keys.k[2 * v + 1] = y1;
  }

  loss_kernel<<<NROW, 256, 0, stream>>>(G, s2, rs, lossAcc, posAcc, keys);
  finalize_kernel<<<1, 1, 0, stream>>>(lossAcc, posAcc, out);
}

// Round 3
// 552.227 us; speedup vs baseline: 1.7052x; 1.7052x over previous
//
#include <hip/hip_runtime.h>
#include <stdint.h>

#define NROW 4096
#define NDIM 512
#define THRS 0.05f

typedef __attribute__((ext_vector_type(8))) __bf16 bf16x8;
typedef __attribute__((ext_vector_type(4))) float f32x4;

// ---------------- workspace layout ----------------
#define XHI_OFF  0ull
#define XHI_SZ   (3ull*4096ull*512ull*2ull)        // 12582912
#define XLO_OFF  (XHI_OFF + XHI_SZ)
#define XLO_SZ   XHI_SZ
#define S2_OFF   (XLO_OFF + XLO_SZ)                // 25165824
#define S2_SZ    (3ull*4096ull*4ull)
#define RS_OFF   (S2_OFF + S2_SZ)
#define RS_SZ    (3ull*4096ull*4ull)
#define G_OFF    (RS_OFF + RS_SZ)                  // 25264128
#define G_SZ     (3ull*4096ull*4096ull*4ull)       // 201326592
#define ACC_OFF  (G_OFF + G_SZ)
#define WS_NEEDED (ACC_OFF + 64ull)

// ---------------- Threefry-2x32 (JAX-exact) ----------------
__host__ __device__ __forceinline__ void tf2x32(uint32_t k0, uint32_t k1,
                                                uint32_t x0, uint32_t x1,
                                                uint32_t* o0, uint32_t* o1) {
  uint32_t ks2 = k0 ^ k1 ^ 0x1BD11BDAu;
  x0 += k0; x1 += k1;
#define TFR(r) { x0 += x1; x1 = (x1 << (r)) | (x1 >> (32 - (r))); x1 ^= x0; }
  TFR(13) TFR(15) TFR(26) TFR(6)
  x0 += k1; x1 += ks2 + 1u;
  TFR(17) TFR(29) TFR(16) TFR(24)
  x0 += ks2; x1 += k0 + 2u;
  TFR(13) TFR(15) TFR(26) TFR(6)
  x0 += k0; x1 += k1 + 3u;
  TFR(17) TFR(29) TFR(16) TFR(24)
  x0 += k1; x1 += ks2 + 4u;
  TFR(13) TFR(15) TFR(26) TFR(6)
  x0 += ks2; x1 += k0 + 5u;
#undef TFR
  *o0 = x0; *o1 = x1;
}

struct Keys { uint32_t k[6]; };

// ---------------- normalize + bf16 hi/lo split: one block per row ----------------
__global__ __launch_bounds__(128) void norm_kernel(const float* __restrict__ X,
                                                   __bf16* __restrict__ Xhi,
                                                   __bf16* __restrict__ Xlo,
                                                   float* __restrict__ s2,
                                                   float* __restrict__ rs) {
  const int row = blockIdx.x;
  const int tid = threadIdx.x;
  const int lane = tid & 63, wid = tid >> 6;
  const float4 v = *(const float4*)(X + (size_t)row * NDIM + tid * 4);
  float ss = v.x*v.x + v.y*v.y + v.z*v.z + v.w*v.w;
  #pragma unroll
  for (int off = 32; off; off >>= 1) ss += __shfl_down(ss, off);
  __shared__ float sw[2];
  if (lane == 0) sw[wid] = ss;
  __syncthreads();
  const float tot = sw[0] + sw[1];
  const float den = fmaxf(sqrtf(tot), 1e-12f);
  float n[4];
  n[0] = v.x / den; n[1] = v.y / den; n[2] = v.z / den; n[3] = v.w / den;

  __bf16 hi[4], lo[4];
  #pragma unroll
  for (int e = 0; e < 4; ++e) {
    hi[e] = (__bf16)n[e];
    lo[e] = (__bf16)(n[e] - (float)hi[e]);
  }
  *(ushort4*)(Xhi + (size_t)row * NDIM + tid * 4) = *(ushort4*)hi;
  *(ushort4*)(Xlo + (size_t)row * NDIM + tid * 4) = *(ushort4*)lo;

  float ps = n[0] + n[1] + n[2] + n[3];
  float p2 = n[0]*n[0] + n[1]*n[1] + n[2]*n[2] + n[3]*n[3];
  #pragma unroll
  for (int off = 32; off; off >>= 1) { ps += __shfl_down(ps, off); p2 += __shfl_down(p2, off); }
  __shared__ float sw2[4];
  if (lane == 0) { sw2[wid] = ps; sw2[2 + wid] = p2; }
  __syncthreads();
  if (tid == 0) { rs[row] = sw2[0] + sw2[1]; s2[row] = sw2[2] + sw2[3]; }
}

// ---------------- split-bf16 MFMA SYRK: C = Xn * Xn^T via A'=[hi,hi,lo], B'=[hi,lo,hi] ----------------
// 128x128 tile, 4 waves (each 64x64 = 4x4 frags of 16x16x32), BK=64, K'=1536.
// Upper-triangular blocks only (bj>=bi); off-diagonal blocks mirror-store.
__global__ __launch_bounds__(256) void gemm_syrk_bf16(const __bf16* __restrict__ Ahi,
                                                      const __bf16* __restrict__ Alo,
                                                      float* __restrict__ C) {
  const int bi = blockIdx.y, bj = blockIdx.x;
  if (bj < bi) return;
  __shared__ __bf16 As[128][64];
  __shared__ __bf16 Bs[128][64];
  const int tid = threadIdx.x;
  const int lane = tid & 63;
  const int wid = tid >> 6;
  const int wr = wid >> 1, wc = wid & 1;

  f32x4 zero4 = {0.f, 0.f, 0.f, 0.f};
  f32x4 acc[4][4];
  #pragma unroll
  for (int m = 0; m < 4; ++m)
    #pragma unroll
    for (int n = 0; n < 4; ++n) acc[m][n] = zero4;

  const int lrow = lane >> 3;        // row within 8-row chunk
  const int lcol = (lane & 7) * 8;   // element col (16B granules)
  const int fr = lane & 15;          // fragment row/col
  const int fk = (lane >> 4) * 8;    // fragment k-offset

  for (int kt = 0; kt < 1536; kt += 64) {
    const int s = kt >> 9;
    const int colk = kt & 511;
    const __bf16* __restrict__ Asrc = (s < 2) ? Ahi : Alo;   // A' = [hi, hi, lo]
    const __bf16* __restrict__ Bsrc = (s == 1) ? Alo : Ahi;  // B' = [hi, lo, hi]
    #pragma unroll
    for (int p = 0; p < 4; ++p) {
      const int c = wid * 4 + p;        // chunk 0..15, covers tile rows c*8..c*8+7
      const int trow = c * 8 + lrow;
      const __bf16* ga = Asrc + (((size_t)(bi * 128 + trow)) << 9) + colk + lcol;
      const __bf16* gb = Bsrc + (((size_t)(bj * 128 + trow)) << 9) + colk + lcol;
      __builtin_amdgcn_global_load_lds((const __attribute__((address_space(1))) void*)ga,
                                       (__attribute__((address_space(3))) void*)((char*)&As[0][0] + c * 1024),
                                       16, 0, 0);
      __builtin_amdgcn_global_load_lds((const __attribute__((address_space(1))) void*)gb,
                                       (__attribute__((address_space(3))) void*)((char*)&Bs[0][0] + c * 1024),
                                       16, 0, 0);
    }
    __syncthreads();
    #pragma unroll
    for (int kk = 0; kk < 64; kk += 32) {
      bf16x8 af[4], bfr[4];
      #pragma unroll
      for (int m = 0; m < 4; ++m)
        af[m] = *(const bf16x8*)&As[wr * 64 + m * 16 + fr][kk + fk];
      #pragma unroll
      for (int n = 0; n < 4; ++n)
        bfr[n] = *(const bf16x8*)&Bs[wc * 64 + n * 16 + fr][kk + fk];
      #pragma unroll
      for (int m = 0; m < 4; ++m)
        #pragma unroll
        for (int n = 0; n < 4; ++n)
          acc[m][n] = __builtin_amdgcn_mfma_f32_16x16x32_bf16(af[m], bfr[n], acc[m][n], 0, 0, 0);
    }
    __syncthreads();
  }

  // C/D layout: col = lane&15, row = (lane>>4)*4 + reg   [m89/m91 verified]
  const int cl = lane & 15;
  const int rg = (lane >> 4) * 4;
  #pragma unroll
  for (int m = 0; m < 4; ++m) {
    #pragma unroll
    for (int n = 0; n < 4; ++n) {
      const int r0 = bi * 128 + wr * 64 + m * 16 + rg;
      const int c0 = bj * 128 + wc * 64 + n * 16 + cl;
      #pragma unroll
      for (int q = 0; q < 4; ++q)
        C[(size_t)(r0 + q) * NROW + c0] = acc[m][n][q];
      if (bi != bj) {
        #pragma unroll
        for (int q = 0; q < 4; ++q)
          C[(size_t)c0 * NROW + (r0 + q)] = acc[m][n][q];
      }
    }
  }
}

// ---------------- fused mask/scan/sample/loss: one block per row ----------------
__global__ __launch_bounds__(256) void loss_kernel(const float* __restrict__ G,
                                                   const float* __restrict__ s2,
                                                   const float* __restrict__ rs,
                                                   double* __restrict__ lossAcc,
                                                   unsigned long long* __restrict__ posAcc,
                                                   Keys keys) {
  __shared__ float sRow[3][NROW];          // 48 KB
  __shared__ unsigned short zlist[NROW];   // 8 KB
  __shared__ int sWaveTot[4];
  __shared__ float sLoss[4];

  const int i = blockIdx.x;
  const int tid = threadIdx.x;
  const int lane = tid & 63, wid = tid >> 6;
  const int j0 = tid * 16;

  #pragma unroll
  for (int v = 0; v < 3; ++v) {
    const float* g = G + ((size_t)v << 24) + ((size_t)i << 12);
    #pragma unroll
    for (int p = 0; p < 4; ++p) {
      const int idx = p * 256 + tid;
      *(float4*)&sRow[v][idx * 4] = *(const float4*)(g + (size_t)idx * 4);
    }
  }
  __syncthreads();

  uint32_t posm = 0;
  #pragma unroll
  for (int e = 0; e < 16; ++e) {
    const int j = j0 + e;
    const bool U = (sRow[0][j] > THRS) | (sRow[1][j] > THRS) | (sRow[2][j] > THRS);
    if (U && (j != i)) posm |= (1u << e);
  }

  const int c = 16 - __popc(posm);
  int inc = c;
  #pragma unroll
  for (int off = 1; off < 64; off <<= 1) {
    const int t = __shfl_up(inc, off);
    if (lane >= off) inc += t;
  }
  if (lane == 63) sWaveTot[wid] = inc;
  __syncthreads();
  int base = inc - c;
  for (int w = 0; w < wid; ++w) base += sWaveTot[w];
  const int cnt = sWaveTot[0] + sWaveTot[1] + sWaveTot[2] + sWaveTot[3];
  int rank = base;
  #pragma unroll
  for (int e = 0; e < 16; ++e) {
    if (!((posm >> e) & 1)) zlist[rank++] = (unsigned short)(j0 + e);
  }
  __syncthreads();

  const float cntf = (float)cnt;
  const int cm1 = cnt - 1;
  float lossSum = 0.0f;

  #pragma unroll
  for (int v = 0; v < 3; ++v) {
    const float* s2v = s2 + v * NROW;
    const float* rsv = rs + v * NROW;
    const float s2i = s2v[i], rsi = rsv[i];
    const float rowA = s2i + 2e-6f * rsi + 5.12e-10f;   // d*eps^2 = 512e-12
    #pragma unroll 4
    for (int e = 0; e < 16; ++e) {
      const int j = j0 + e;
      const float g = sRow[v][j];
      const float d2 = rowA + (s2v[j] - 2e-6f * rsv[j]) - 2.0f * g;
      sRow[v][j] = sqrtf(fmaxf(d2, 0.0f));
    }
    __syncthreads();

    const uint32_t fk0 = keys.k[2 * v], fk1 = keys.k[2 * v + 1];
    const uint32_t tbase = (uint32_t)i * 4096u + (uint32_t)j0;
    for (int e = 0; e < 16; ++e) {
      if ((posm >> e) & 1) {
        const uint32_t t = tbase + e;
        uint32_t y0, y1, bits;
        if (i < 2048) { tf2x32(fk0, fk1, t, t + 8388608u, &y0, &y1); bits = y0; }
        else          { tf2x32(fk0, fk1, t - 8388608u, t, &y0, &y1); bits = y1; }
        const float u = __uint_as_float((bits >> 9) | 0x3F800000u) - 1.0f;
        int r = (int)(u * cntf);
        r = min(r, cm1);
        const int n = zlist[r];
        const float dan = sRow[v][n];
        const float dij = sRow[v][j0 + e];
        lossSum += fmaxf(dij - dan + 1.0f, 0.0f);
      }
    }
    __syncthreads();
  }

  #pragma unroll
  for (int off = 32; off; off >>= 1) lossSum += __shfl_down(lossSum, off);
  if (lane == 0) sLoss[wid] = lossSum;
  __syncthreads();
  if (tid == 0) {
    const double tot = (double)sLoss[0] + (double)sLoss[1] + (double)sLoss[2] + (double)sLoss[3];
    atomicAdd(lossAcc, tot);
    atomicAdd(posAcc, (unsigned long long)(NROW - cnt));
  }
}

__global__ void finalize_kernel(const double* __restrict__ lossAcc,
                                const unsigned long long* __restrict__ posAcc,
                                float* __restrict__ out) {
  if (threadIdx.x == 0 && blockIdx.x == 0) {
    out[0] = (float)(lossAcc[0] / (double)posAcc[0]);
  }
}

// ---------------- launch ----------------
extern "C" void kernel_launch(void* const* d_in, const int* in_sizes, int n_in,
                              void* d_out, int out_size, void* d_ws, size_t ws_size,
                              hipStream_t stream) {
  if (ws_size < WS_NEEDED) return;

  const float* Xs[3] = { (const float*)d_in[0], (const float*)d_in[1], (const float*)d_in[2] };
  char* ws = (char*)d_ws;
  __bf16* Xhi = (__bf16*)(ws + XHI_OFF);
  __bf16* Xlo = (__bf16*)(ws + XLO_OFF);
  float* s2 = (float*)(ws + S2_OFF);
  float* rs = (float*)(ws + RS_OFF);
  float* G  = (float*)(ws + G_OFF);
  double* lossAcc = (double*)(ws + ACC_OFF);
  unsigned long long* posAcc = (unsigned long long*)(ws + ACC_OFF + 8);
  float* out = (float*)d_out;

  hipMemsetAsync(ws + ACC_OFF, 0, 16, stream);

  for (int v = 0; v < 3; ++v)
    norm_kernel<<<NROW, 128, 0, stream>>>(Xs[v],
                                          Xhi + (size_t)v * NROW * NDIM,
                                          Xlo + (size_t)v * NROW * NDIM,
                                          s2 + v * NROW, rs + v * NROW);

  for (int v = 0; v < 3; ++v)
    gemm_syrk_bf16<<<dim3(32, 32), 256, 0, stream>>>(Xhi + (size_t)v * NROW * NDIM,
                                                     Xlo + (size_t)v * NROW * NDIM,
                                                     G + ((size_t)v << 24));

  Keys keys;
  for (uint32_t v = 0; v < 3; ++v) {
    uint32_t y0, y1;
    tf2x32(0u, 42u, 0u, v, &y0, &y1);
    keys.k[2 * v] = y0; keys.k[2 * v + 1] = y1;
  }

  loss_kernel<<<NROW, 256, 0, stream>>>(G, s2, rs, lossAcc, posAcc, keys);
  finalize_kernel<<<1, 1, 0, stream>>>(lossAcc, posAcc, out);
}

// Round 10
// 363.643 us; speedup vs baseline: 2.5896x; 1.5186x over previous
//
#include <hip/hip_runtime.h>
#include <stdint.h>

#define NROW 4096
#define NDIM 512
#define THRS 0.05f

typedef __attribute__((ext_vector_type(8))) __bf16 bf16x8;
typedef __attribute__((ext_vector_type(4))) float f32x4;

// ---------------- workspace layout ----------------
#define XHI_OFF  0ull
#define XHI_SZ   (3ull*4096ull*512ull*2ull)        // 12582912
#define XLO_OFF  (XHI_OFF + XHI_SZ)
#define XLO_SZ   XHI_SZ
#define RT_OFF   (XLO_OFF + XLO_SZ)                // rowT: s2 + 2e-6*rs + d*eps^2
#define RT_SZ    (3ull*4096ull*4ull)
#define CT_OFF   (RT_OFF + RT_SZ)                  // colT: s2 - 2e-6*rs
#define CT_SZ    (3ull*4096ull*4ull)
#define G_OFF    (CT_OFF + CT_SZ)
#define G_SZ     (3ull*4096ull*4096ull*4ull)       // 201326592
#define ACC_OFF  (G_OFF + G_SZ)
#define WS_NEEDED (ACC_OFF + 64ull)

// ---------------- Threefry-2x32 (JAX-exact) ----------------
__host__ __device__ __forceinline__ void tf2x32(uint32_t k0, uint32_t k1,
                                                uint32_t x0, uint32_t x1,
                                                uint32_t* o0, uint32_t* o1) {
  uint32_t ks2 = k0 ^ k1 ^ 0x1BD11BDAu;
  x0 += k0; x1 += k1;
#define TFR(r) { x0 += x1; x1 = (x1 << (r)) | (x1 >> (32 - (r))); x1 ^= x0; }
  TFR(13) TFR(15) TFR(26) TFR(6)
  x0 += k1; x1 += ks2 + 1u;
  TFR(17) TFR(29) TFR(16) TFR(24)
  x0 += ks2; x1 += k0 + 2u;
  TFR(13) TFR(15) TFR(26) TFR(6)
  x0 += k0; x1 += k1 + 3u;
  TFR(17) TFR(29) TFR(16) TFR(24)
  x0 += k1; x1 += ks2 + 4u;
  TFR(13) TFR(15) TFR(26) TFR(6)
  x0 += ks2; x1 += k0 + 5u;
#undef TFR
  *o0 = x0; *o1 = x1;
}

struct Keys { uint32_t k[6]; };

// ---------------- normalize + bf16 hi/lo split: one block per row ----------------
__global__ __launch_bounds__(128) void norm_kernel(const float* __restrict__ X,
                                                   __bf16* __restrict__ Xhi,
                                                   __bf16* __restrict__ Xlo,
                                                   float* __restrict__ rowT,
                                                   float* __restrict__ colT) {
  const int row = blockIdx.x;
  const int tid = threadIdx.x;
  const int lane = tid & 63, wid = tid >> 6;
  const float4 v = *(const float4*)(X + (size_t)row * NDIM + tid * 4);
  float ss = v.x*v.x + v.y*v.y + v.z*v.z + v.w*v.w;
  #pragma unroll
  for (int off = 32; off; off >>= 1) ss += __shfl_down(ss, off);
  __shared__ float sw[2];
  if (lane == 0) sw[wid] = ss;
  __syncthreads();
  const float tot = sw[0] + sw[1];
  const float den = fmaxf(sqrtf(tot), 1e-12f);
  float n[4];
  n[0] = v.x / den; n[1] = v.y / den; n[2] = v.z / den; n[3] = v.w / den;

  __bf16 hi[4], lo[4];
  #pragma unroll
  for (int e = 0; e < 4; ++e) {
    hi[e] = (__bf16)n[e];
    lo[e] = (__bf16)(n[e] - (float)hi[e]);
  }
  *(ushort4*)(Xhi + (size_t)row * NDIM + tid * 4) = *(ushort4*)hi;
  *(ushort4*)(Xlo + (size_t)row * NDIM + tid * 4) = *(ushort4*)lo;

  float ps = n[0] + n[1] + n[2] + n[3];
  float p2 = n[0]*n[0] + n[1]*n[1] + n[2]*n[2] + n[3]*n[3];
  #pragma unroll
  for (int off = 32; off; off >>= 1) { ps += __shfl_down(ps, off); p2 += __shfl_down(p2, off); }
  __shared__ float sw2[4];
  if (lane == 0) { sw2[wid] = ps; sw2[2 + wid] = p2; }
  __syncthreads();
  if (tid == 0) {
    const float rs = sw2[0] + sw2[1];
    const float s2 = sw2[2] + sw2[3];
    rowT[row] = s2 + 2e-6f * rs + 5.12e-10f;   // s2_i + 2eps*rs_i + d*eps^2
    colT[row] = s2 - 2e-6f * rs;               // s2_j - 2eps*rs_j
  }
}

// ---------------- split-bf16 MFMA SYRK, flattened triangular grid over 3 views ----------------
// tile 128x128, 4 waves (64x64 each), BK=64, K'=1536 (A'=[hi,hi,lo], B'=[hi,lo,hi]).
__global__ __launch_bounds__(256) void gemm_syrk_bf16(const __bf16* __restrict__ XhiBase,
                                                      const __bf16* __restrict__ XloBase,
                                                      float* __restrict__ CBase) {
  // decode view + triangular tile (bj >= bi), 528 tiles per view
  const int bx = blockIdx.x;
  const int v = bx / 528;
  const int t = bx - v * 528;
  int bi = (int)((65.0f - sqrtf(4225.0f - 8.0f * (float)t)) * 0.5f);
  while ((bi + 1) * (65 - (bi + 1)) / 2 <= t) ++bi;
  while (bi * (65 - bi) / 2 > t) --bi;
  const int bj = bi + (t - bi * (65 - bi) / 2);

  const __bf16* __restrict__ Ahi = XhiBase + (size_t)v * NROW * NDIM;
  const __bf16* __restrict__ Alo = XloBase + (size_t)v * NROW * NDIM;
  float* __restrict__ C = CBase + ((size_t)v << 24);

  __shared__ __bf16 As[128][64];
  __shared__ __bf16 Bs[128][64];
  const int tid = threadIdx.x;
  const int lane = tid & 63;
  const int wid = tid >> 6;
  const int wr = wid >> 1, wc = wid & 1;

  f32x4 zero4 = {0.f, 0.f, 0.f, 0.f};
  f32x4 acc[4][4];
  #pragma unroll
  for (int m = 0; m < 4; ++m)
    #pragma unroll
    for (int n = 0; n < 4; ++n) acc[m][n] = zero4;

  const int lrow = lane >> 3;
  const int lcol = (lane & 7) * 8;
  const int fr = lane & 15;
  const int fk = (lane >> 4) * 8;

  for (int kt = 0; kt < 1536; kt += 64) {
    const int s = kt >> 9;
    const int colk = kt & 511;
    const __bf16* __restrict__ Asrc = (s < 2) ? Ahi : Alo;   // A' = [hi, hi, lo]
    const __bf16* __restrict__ Bsrc = (s == 1) ? Alo : Ahi;  // B' = [hi, lo, hi]
    #pragma unroll
    for (int p = 0; p < 4; ++p) {
      const int c = wid * 4 + p;
      const int trow = c * 8 + lrow;
      const __bf16* ga = Asrc + (((size_t)(bi * 128 + trow)) << 9) + colk + lcol;
      const __bf16* gb = Bsrc + (((size_t)(bj * 128 + trow)) << 9) + colk + lcol;
      __builtin_amdgcn_global_load_lds((const __attribute__((address_space(1))) void*)ga,
                                       (__attribute__((address_space(3))) void*)((char*)&As[0][0] + c * 1024),
                                       16, 0, 0);
      __builtin_amdgcn_global_load_lds((const __attribute__((address_space(1))) void*)gb,
                                       (__attribute__((address_space(3))) void*)((char*)&Bs[0][0] + c * 1024),
                                       16, 0, 0);
    }
    __syncthreads();
    #pragma unroll
    for (int kk = 0; kk < 64; kk += 32) {
      bf16x8 af[4], bfr[4];
      #pragma unroll
      for (int m = 0; m < 4; ++m)
        af[m] = *(const bf16x8*)&As[wr * 64 + m * 16 + fr][kk + fk];
      #pragma unroll
      for (int n = 0; n < 4; ++n)
        bfr[n] = *(const bf16x8*)&Bs[wc * 64 + n * 16 + fr][kk + fk];
      #pragma unroll
      for (int m = 0; m < 4; ++m)
        #pragma unroll
        for (int n = 0; n < 4; ++n)
          acc[m][n] = __builtin_amdgcn_mfma_f32_16x16x32_bf16(af[m], bfr[n], acc[m][n], 0, 0, 0);
    }
    __syncthreads();
  }

  // C/D layout: col = lane&15, row = (lane>>4)*4 + reg
  const int cl = lane & 15;
  const int rg = (lane >> 4) * 4;
  #pragma unroll
  for (int m = 0; m < 4; ++m) {
    #pragma unroll
    for (int n = 0; n < 4; ++n) {
      const int r0 = bi * 128 + wr * 64 + m * 16 + rg;
      const int c0 = bj * 128 + wc * 64 + n * 16 + cl;
      #pragma unroll
      for (int q = 0; q < 4; ++q)
        C[(size_t)(r0 + q) * NROW + c0] = acc[m][n][q];
      if (bi != bj) {
        #pragma unroll
        for (int q = 0; q < 4; ++q)
          C[(size_t)c0 * NROW + (r0 + q)] = acc[m][n][q];
      }
    }
  }
}

// ---------------- fused mask/scan/compact/sample/loss: one block per row ----------------
// Element mapping: thread t owns j in {p*1024 + t*4 + e : p<4, e<4} (all accesses float4).
__global__ __launch_bounds__(256, 4) void loss_kernel(const float* __restrict__ G,
                                                      const float* __restrict__ rowT,
                                                      const float* __restrict__ colT,
                                                      double* __restrict__ lossAcc,
                                                      unsigned long long* __restrict__ posAcc,
                                                      Keys keys) {
  __shared__ float sBuf[NROW];              // 16 KB: current view D row
  __shared__ unsigned short zlist[NROW];    // 8 KB: zero positions (sorted)
  __shared__ unsigned short plist[NROW];    // 8 KB: positive positions (sorted)
  __shared__ unsigned char nib[1024];       // zero-nibble per 4-element group
  __shared__ int sWaveTot[4];
  __shared__ float sLoss[4];

  const int i = blockIdx.x;
  const int tid = threadIdx.x;
  const int lane = tid & 63, wid = tid >> 6;

  // ---- phase 1: union mask straight from global (no LDS) ----
  {
    bool posb[4][4];
    #pragma unroll
    for (int p = 0; p < 4; ++p) {
      const int j4 = p * 1024 + tid * 4;
      #pragma unroll
      for (int e = 0; e < 4; ++e) posb[p][e] = false;
      #pragma unroll
      for (int v = 0; v < 3; ++v) {
        const float4 g = *(const float4*)(G + ((size_t)v << 24) + ((size_t)i << 12) + j4);
        posb[p][0] |= (g.x > THRS); posb[p][1] |= (g.y > THRS);
        posb[p][2] |= (g.z > THRS); posb[p][3] |= (g.w > THRS);
      }
      unsigned int z = 0;
      #pragma unroll
      for (int e = 0; e < 4; ++e) {
        const int j = j4 + e;
        const bool pos = posb[p][e] && (j != i);
        if (!pos) z |= (1u << e);
      }
      nib[p * 256 + tid] = (unsigned char)z;   // group index g = j/4 = p*256+tid
    }
  }
  __syncthreads();

  // ---- phase 2: block scan over 1024 groups (thread t owns groups 4t..4t+3) ----
  const uchar4 myn = *(const uchar4*)&nib[tid * 4];
  const int cz = __popc((unsigned)myn.x) + __popc((unsigned)myn.y) +
                 __popc((unsigned)myn.z) + __popc((unsigned)myn.w);
  int inc = cz;
  #pragma unroll
  for (int off = 1; off < 64; off <<= 1) {
    const int s = __shfl_up(inc, off);
    if (lane >= off) inc += s;
  }
  if (lane == 63) sWaveTot[wid] = inc;
  __syncthreads();
  int base = inc - cz;
  for (int w = 0; w < wid; ++w) base += sWaveTot[w];
  const int cnt = sWaveTot[0] + sWaveTot[1] + sWaveTot[2] + sWaveTot[3];
  {
    int zr = base;                     // zeros strictly before current j
    const unsigned char nn[4] = { myn.x, myn.y, myn.z, myn.w };
    #pragma unroll
    for (int q = 0; q < 4; ++q) {
      const int jb = tid * 16 + q * 4;
      #pragma unroll
      for (int e = 0; e < 4; ++e) {
        const int j = jb + e;
        if ((nn[q] >> e) & 1) { zlist[zr] = (unsigned short)j; ++zr; }
        else                  { plist[j - zr] = (unsigned short)j; }
      }
    }
  }
  __syncthreads();

  const int npos = NROW - cnt;
  const float cntf = (float)cnt;
  const int cm1 = cnt - 1;
  float lossSum = 0.0f;

  // ---- phase 3: per view, stage+transform row then dense sampling over plist ----
  #pragma unroll
  for (int v = 0; v < 3; ++v) {
    const float rT = rowT[v * NROW + i];
    const float* __restrict__ cT = colT + v * NROW;
    const float* __restrict__ g = G + ((size_t)v << 24) + ((size_t)i << 12);
    #pragma unroll
    for (int p = 0; p < 4; ++p) {
      const int j4 = p * 1024 + tid * 4;
      const float4 gg = *(const float4*)(g + j4);
      const float4 ct = *(const float4*)(cT + j4);
      float4 d;
      d.x = sqrtf(fmaxf((rT + ct.x) - 2.0f * gg.x, 0.0f));
      d.y = sqrtf(fmaxf((rT + ct.y) - 2.0f * gg.y, 0.0f));
      d.z = sqrtf(fmaxf((rT + ct.z) - 2.0f * gg.z, 0.0f));
      d.w = sqrtf(fmaxf((rT + ct.w) - 2.0f * gg.w, 0.0f));
      *(float4*)&sBuf[j4] = d;
    }
    __syncthreads();

    const uint32_t fk0 = keys.k[2 * v], fk1 = keys.k[2 * v + 1];
    const uint32_t tbase = (uint32_t)i * 4096u;
    for (int k = tid; k < npos; k += 256) {
      const int j = plist[k];
      const uint32_t t32 = tbase + (uint32_t)j;
      uint32_t y0, y1, bits;
      if (i < 2048) { tf2x32(fk0, fk1, t32, t32 + 8388608u, &y0, &y1); bits = y0; }
      else          { tf2x32(fk0, fk1, t32 - 8388608u, t32, &y0, &y1); bits = y1; }
      const float u = __uint_as_float((bits >> 9) | 0x3F800000u) - 1.0f;
      int r = (int)(u * cntf);
      r = min(r, cm1);
      const int n = zlist[r];
      lossSum += fmaxf(sBuf[j] - sBuf[n] + 1.0f, 0.0f);
    }
    __syncthreads();   // before next view overwrites sBuf
  }

  // ---- block reduce ----
  #pragma unroll
  for (int off = 32; off; off >>= 1) lossSum += __shfl_down(lossSum, off);
  if (lane == 0) sLoss[wid] = lossSum;
  __syncthreads();
  if (tid == 0) {
    const double tot = (double)sLoss[0] + (double)sLoss[1] + (double)sLoss[2] + (double)sLoss[3];
    atomicAdd(lossAcc, tot);
    atomicAdd(posAcc, (unsigned long long)npos);
  }
}

__global__ void finalize_kernel(const double* __restrict__ lossAcc,
                                const unsigned long long* __restrict__ posAcc,
                                float* __restrict__ out) {
  if (threadIdx.x == 0 && blockIdx.x == 0) {
    out[0] = (float)(lossAcc[0] / (double)posAcc[0]);
  }
}

// ---------------- launch ----------------
extern "C" void kernel_launch(void* const* d_in, const int* in_sizes, int n_in,
                              void* d_out, int out_size, void* d_ws, size_t ws_size,
                              hipStream_t stream) {
  if (ws_size < WS_NEEDED) return;

  const float* Xs[3] = { (const float*)d_in[0], (const float*)d_in[1], (const float*)d_in[2] };
  char* ws = (char*)d_ws;
  __bf16* Xhi = (__bf16*)(ws + XHI_OFF);
  __bf16* Xlo = (__bf16*)(ws + XLO_OFF);
  float* rowT = (float*)(ws + RT_OFF);
  float* colT = (float*)(ws + CT_OFF);
  float* G  = (float*)(ws + G_OFF);
  double* lossAcc = (double*)(ws + ACC_OFF);
  unsigned long long* posAcc = (unsigned long long*)(ws + ACC_OFF + 8);
  float* out = (float*)d_out;

  hipMemsetAsync(ws + ACC_OFF, 0, 16, stream);

  for (int v = 0; v < 3; ++v)
    norm_kernel<<<NROW, 128, 0, stream>>>(Xs[v],
                                          Xhi + (size_t)v * NROW * NDIM,
                                          Xlo + (size_t)v * NROW * NDIM,
                                          rowT + v * NROW, colT + v * NROW);

  gemm_syrk_bf16<<<3 * 528, 256, 0, stream>>>(Xhi, Xlo, G);

  Keys keys;
  for (uint32_t v = 0; v < 3; ++v) {
    uint32_t y0, y1;
    tf2x32(0u, 42u, 0u, v, &y0, &y1);
    keys.k[2 * v] = y0; keys.k[2 * v + 1] = y1;
  }

  loss_kernel<<<NROW, 256, 0, stream>>>(G, rowT, colT, lossAcc, posAcc, keys);
  finalize_kernel<<<1, 1, 0, stream>>>(lossAcc, posAcc, out);
}

// Round 11
// 359.104 us; speedup vs baseline: 2.6223x; 1.0126x over previous
//
#include <hip/hip_runtime.h>
#include <stdint.h>

#define NROW 4096
#define NDIM 512
#define THRS 0.05f

typedef __attribute__((ext_vector_type(8))) __bf16 bf16x8;
typedef __attribute__((ext_vector_type(4))) float f32x4;

// ---------------- workspace layout ----------------
#define XHI_OFF  0ull
#define XHI_SZ   (3ull*4096ull*512ull*2ull)        // 12582912
#define XLO_OFF  (XHI_OFF + XHI_SZ)
#define XLO_SZ   XHI_SZ
#define RT_OFF   (XLO_OFF + XLO_SZ)                // rowT: s2 + 2e-6*rs + d*eps^2
#define RT_SZ    (3ull*4096ull*4ull)
#define CT_OFF   (RT_OFF + RT_SZ)                  // colT: s2 - 2e-6*rs
#define CT_SZ    (3ull*4096ull*4ull)
#define G_OFF    (CT_OFF + CT_SZ)
#define G_SZ     (3ull*4096ull*4096ull*4ull)       // 201326592
#define ACC_OFF  (G_OFF + G_SZ)
#define WS_NEEDED (ACC_OFF + 64ull)

// ---------------- Threefry-2x32 (JAX-exact) ----------------
__host__ __device__ __forceinline__ void tf2x32(uint32_t k0, uint32_t k1,
                                                uint32_t x0, uint32_t x1,
                                                uint32_t* o0, uint32_t* o1) {
  uint32_t ks2 = k0 ^ k1 ^ 0x1BD11BDAu;
  x0 += k0; x1 += k1;
#define TFR(r) { x0 += x1; x1 = (x1 << (r)) | (x1 >> (32 - (r))); x1 ^= x0; }
  TFR(13) TFR(15) TFR(26) TFR(6)
  x0 += k1; x1 += ks2 + 1u;
  TFR(17) TFR(29) TFR(16) TFR(24)
  x0 += ks2; x1 += k0 + 2u;
  TFR(13) TFR(15) TFR(26) TFR(6)
  x0 += k0; x1 += k1 + 3u;
  TFR(17) TFR(29) TFR(16) TFR(24)
  x0 += k1; x1 += ks2 + 4u;
  TFR(13) TFR(15) TFR(26) TFR(6)
  x0 += ks2; x1 += k0 + 5u;
#undef TFR
  *o0 = x0; *o1 = x1;
}

struct Keys { uint32_t k[6]; };

// ---------------- normalize + bf16 hi/lo split: one block per row ----------------
__global__ __launch_bounds__(128) void norm_kernel(const float* __restrict__ X,
                                                   __bf16* __restrict__ Xhi,
                                                   __bf16* __restrict__ Xlo,
                                                   float* __restrict__ rowT,
                                                   float* __restrict__ colT) {
  const int row = blockIdx.x;
  const int tid = threadIdx.x;
  const int lane = tid & 63, wid = tid >> 6;
  const float4 v = *(const float4*)(X + (size_t)row * NDIM + tid * 4);
  float ss = v.x*v.x + v.y*v.y + v.z*v.z + v.w*v.w;
  #pragma unroll
  for (int off = 32; off; off >>= 1) ss += __shfl_down(ss, off);
  __shared__ float sw[2];
  if (lane == 0) sw[wid] = ss;
  __syncthreads();
  const float tot = sw[0] + sw[1];
  const float den = fmaxf(sqrtf(tot), 1e-12f);
  float n[4];
  n[0] = v.x / den; n[1] = v.y / den; n[2] = v.z / den; n[3] = v.w / den;

  __bf16 hi[4], lo[4];
  #pragma unroll
  for (int e = 0; e < 4; ++e) {
    hi[e] = (__bf16)n[e];
    lo[e] = (__bf16)(n[e] - (float)hi[e]);
  }
  *(ushort4*)(Xhi + (size_t)row * NDIM + tid * 4) = *(ushort4*)hi;
  *(ushort4*)(Xlo + (size_t)row * NDIM + tid * 4) = *(ushort4*)lo;

  float ps = n[0] + n[1] + n[2] + n[3];
  float p2 = n[0]*n[0] + n[1]*n[1] + n[2]*n[2] + n[3]*n[3];
  #pragma unroll
  for (int off = 32; off; off >>= 1) { ps += __shfl_down(ps, off); p2 += __shfl_down(p2, off); }
  __shared__ float sw2[4];
  if (lane == 0) { sw2[wid] = ps; sw2[2 + wid] = p2; }
  __syncthreads();
  if (tid == 0) {
    const float rs = sw2[0] + sw2[1];
    const float s2 = sw2[2] + sw2[3];
    rowT[row] = s2 + 2e-6f * rs + 5.12e-10f;   // s2_i + 2eps*rs_i + d*eps^2
    colT[row] = s2 - 2e-6f * rs;               // s2_j - 2eps*rs_j
  }
}

// ---------------- split-bf16 MFMA SYRK, flattened triangular grid over 3 views ----------------
// tile 128x128, 4 waves (64x64 each), BK=64, K'=1536 (A'=[hi,hi,lo], B'=[hi,lo,hi]).
// XCD-swizzled block index; LDS-staged coalesced epilogue (normal + mirrored).
__global__ __launch_bounds__(256) void gemm_syrk_bf16(const __bf16* __restrict__ XhiBase,
                                                      const __bf16* __restrict__ XloBase,
                                                      float* __restrict__ CBase) {
  // XCD-aware bijective swizzle: 1584 % 8 == 0 -> consecutive logical tiles per XCD
  const int orig = blockIdx.x;
  const int bx = (orig & 7) * (1584 >> 3) + (orig >> 3);

  // decode view + triangular tile (bj >= bi), 528 tiles per view
  const int v = bx / 528;
  const int t = bx - v * 528;
  int bi = (int)((65.0f - sqrtf(4225.0f - 8.0f * (float)t)) * 0.5f);
  while ((bi + 1) * (65 - (bi + 1)) / 2 <= t) ++bi;
  while (bi * (65 - bi) / 2 > t) --bi;
  const int bj = bi + (t - bi * (65 - bi) / 2);

  const __bf16* __restrict__ Ahi = XhiBase + (size_t)v * NROW * NDIM;
  const __bf16* __restrict__ Alo = XloBase + (size_t)v * NROW * NDIM;
  float* __restrict__ C = CBase + ((size_t)v << 24);

  // unioned LDS: k-loop As/Bs (32 KB) ; epilogue float[64][136] / float[128][68] (34 KB)
  __shared__ __align__(16) char smemRaw[34816];
  __bf16 (*As)[64] = (__bf16 (*)[64])smemRaw;               // 128x64 bf16 = 16 KB
  __bf16 (*Bs)[64] = (__bf16 (*)[64])(smemRaw + 16384);     // 16 KB

  const int tid = threadIdx.x;
  const int lane = tid & 63;
  const int wid = tid >> 6;
  const int wr = wid >> 1, wc = wid & 1;

  f32x4 zero4 = {0.f, 0.f, 0.f, 0.f};
  f32x4 acc[4][4];
  #pragma unroll
  for (int m = 0; m < 4; ++m)
    #pragma unroll
    for (int n = 0; n < 4; ++n) acc[m][n] = zero4;

  const int lrow = lane >> 3;
  const int lcol = (lane & 7) * 8;
  const int fr = lane & 15;
  const int fk = (lane >> 4) * 8;

  for (int kt = 0; kt < 1536; kt += 64) {
    const int s = kt >> 9;
    const int colk = kt & 511;
    const __bf16* __restrict__ Asrc = (s < 2) ? Ahi : Alo;   // A' = [hi, hi, lo]
    const __bf16* __restrict__ Bsrc = (s == 1) ? Alo : Ahi;  // B' = [hi, lo, hi]
    #pragma unroll
    for (int p = 0; p < 4; ++p) {
      const int c = wid * 4 + p;
      const int trow = c * 8 + lrow;
      const __bf16* ga = Asrc + (((size_t)(bi * 128 + trow)) << 9) + colk + lcol;
      const __bf16* gb = Bsrc + (((size_t)(bj * 128 + trow)) << 9) + colk + lcol;
      __builtin_amdgcn_global_load_lds((const __attribute__((address_space(1))) void*)ga,
                                       (__attribute__((address_space(3))) void*)(smemRaw + c * 1024),
                                       16, 0, 0);
      __builtin_amdgcn_global_load_lds((const __attribute__((address_space(1))) void*)gb,
                                       (__attribute__((address_space(3))) void*)(smemRaw + 16384 + c * 1024),
                                       16, 0, 0);
    }
    __syncthreads();
    #pragma unroll
    for (int kk = 0; kk < 64; kk += 32) {
      bf16x8 af[4], bfr[4];
      #pragma unroll
      for (int m = 0; m < 4; ++m)
        af[m] = *(const bf16x8*)&As[wr * 64 + m * 16 + fr][kk + fk];
      #pragma unroll
      for (int n = 0; n < 4; ++n)
        bfr[n] = *(const bf16x8*)&Bs[wc * 64 + n * 16 + fr][kk + fk];
      #pragma unroll
      for (int m = 0; m < 4; ++m)
        #pragma unroll
        for (int n = 0; n < 4; ++n)
          acc[m][n] = __builtin_amdgcn_mfma_f32_16x16x32_bf16(af[m], bfr[n], acc[m][n], 0, 0, 0);
    }
    __syncthreads();
  }

  // ---- LDS-staged coalesced epilogue ----
  // C/D frag layout: col = lane&15, row = (lane>>4)*4 + reg  [m89/m91 verified]
  const int cl = lane & 15;
  const int rg = (lane >> 4) * 4;
  float (*Ls)[136] = (float (*)[136])smemRaw;   // 64 x 136 (row-chunk, padded, 16B-aligned rows)
  float (*Lt)[68]  = (float (*)[68])smemRaw;    // 128 x 68 (transposed chunk)

  __syncthreads();   // k-loop smem reads done before reuse
  #pragma unroll
  for (int r = 0; r < 2; ++r) {
    if (r) __syncthreads();
    if (wr == r) {
      #pragma unroll
      for (int m = 0; m < 4; ++m)
        #pragma unroll
        for (int n = 0; n < 4; ++n)
          #pragma unroll
          for (int q = 0; q < 4; ++q)
            Ls[m * 16 + rg + q][wc * 64 + n * 16 + cl] = acc[m][n][q];
    }
    __syncthreads();
    #pragma unroll
    for (int q = 0; q < 8; ++q) {
      const int idx = q * 256 + tid;       // 2048 float4 = 64 rows x 32
      const int row = idx >> 5, c4 = idx & 31;
      *(float4*)&C[(size_t)(bi * 128 + r * 64 + row) * NROW + bj * 128 + c4 * 4] =
          *(const float4*)&Ls[row][c4 * 4];
    }
    if (bi != bj) {
      __syncthreads();
      if (wr == r) {
        #pragma unroll
        for (int m = 0; m < 4; ++m)
          #pragma unroll
          for (int n = 0; n < 4; ++n)
            #pragma unroll
            for (int q = 0; q < 4; ++q)
              Lt[wc * 64 + n * 16 + cl][m * 16 + rg + q] = acc[m][n][q];
      }
      __syncthreads();
      #pragma unroll
      for (int q = 0; q < 8; ++q) {
        const int idx = q * 256 + tid;     // 2048 float4 = 128 rows x 16
        const int mrow = idx >> 4, c4 = idx & 15;
        *(float4*)&C[(size_t)(bj * 128 + mrow) * NROW + bi * 128 + r * 64 + c4 * 4] =
            *(const float4*)&Lt[mrow][c4 * 4];
      }
    }
  }
}

// ---------------- fused mask/scan/compact/sample/loss: one block per row ----------------
// Element mapping: thread t owns j in {p*1024 + t*4 + e : p<4, e<4} (all accesses float4).
__global__ __launch_bounds__(256, 4) void loss_kernel(const float* __restrict__ G,
                                                      const float* __restrict__ rowT,
                                                      const float* __restrict__ colT,
                                                      double* __restrict__ lossAcc,
                                                      unsigned long long* __restrict__ posAcc,
                                                      Keys keys) {
  __shared__ float sBuf[NROW];              // 16 KB: current view D row
  __shared__ unsigned short zlist[NROW];    // 8 KB: zero positions (sorted)
  __shared__ unsigned short plist[NROW];    // 8 KB: positive positions (sorted)
  __shared__ unsigned char nib[1024];       // zero-nibble per 4-element group
  __shared__ int sWaveTot[4];
  __shared__ float sLoss[4];

  const int i = blockIdx.x;
  const int tid = threadIdx.x;
  const int lane = tid & 63, wid = tid >> 6;

  // ---- phase 1: union mask straight from global (no LDS) ----
  {
    bool posb[4][4];
    #pragma unroll
    for (int p = 0; p < 4; ++p) {
      const int j4 = p * 1024 + tid * 4;
      #pragma unroll
      for (int e = 0; e < 4; ++e) posb[p][e] = false;
      #pragma unroll
      for (int v = 0; v < 3; ++v) {
        const float4 g = *(const float4*)(G + ((size_t)v << 24) + ((size_t)i << 12) + j4);
        posb[p][0] |= (g.x > THRS); posb[p][1] |= (g.y > THRS);
        posb[p][2] |= (g.z > THRS); posb[p][3] |= (g.w > THRS);
      }
      unsigned int z = 0;
      #pragma unroll
      for (int e = 0; e < 4; ++e) {
        const int j = j4 + e;
        const bool pos = posb[p][e] && (j != i);
        if (!pos) z |= (1u << e);
      }
      nib[p * 256 + tid] = (unsigned char)z;   // group index g = j/4 = p*256+tid
    }
  }
  __syncthreads();

  // ---- phase 2: block scan over 1024 groups (thread t owns groups 4t..4t+3) ----
  const uchar4 myn = *(const uchar4*)&nib[tid * 4];
  const int cz = __popc((unsigned)myn.x) + __popc((unsigned)myn.y) +
                 __popc((unsigned)myn.z) + __popc((unsigned)myn.w);
  int inc = cz;
  #pragma unroll
  for (int off = 1; off < 64; off <<= 1) {
    const int s = __shfl_up(inc, off);
    if (lane >= off) inc += s;
  }
  if (lane == 63) sWaveTot[wid] = inc;
  __syncthreads();
  int base = inc - cz;
  for (int w = 0; w < wid; ++w) base += sWaveTot[w];
  const int cnt = sWaveTot[0] + sWaveTot[1] + sWaveTot[2] + sWaveTot[3];
  {
    int zr = base;                     // zeros strictly before current j
    const unsigned char nn[4] = { myn.x, myn.y, myn.z, myn.w };
    #pragma unroll
    for (int q = 0; q < 4; ++q) {
      const int jb = tid * 16 + q * 4;
      #pragma unroll
      for (int e = 0; e < 4; ++e) {
        const int j = jb + e;
        if ((nn[q] >> e) & 1) { zlist[zr] = (unsigned short)j; ++zr; }
        else                  { plist[j - zr] = (unsigned short)j; }
      }
    }
  }
  __syncthreads();

  const int npos = NROW - cnt;
  const float cntf = (float)cnt;
  const int cm1 = cnt - 1;
  float lossSum = 0.0f;

  // ---- phase 3: per view, stage+transform row then dense sampling over plist ----
  #pragma unroll
  for (int v = 0; v < 3; ++v) {
    const float rT = rowT[v * NROW + i];
    const float* __restrict__ cT = colT + v * NROW;
    const float* __restrict__ g = G + ((size_t)v << 24) + ((size_t)i << 12);
    #pragma unroll
    for (int p = 0; p < 4; ++p) {
      const int j4 = p * 1024 + tid * 4;
      const float4 gg = *(const float4*)(g + j4);
      const float4 ct = *(const float4*)(cT + j4);
      float4 d;
      d.x = sqrtf(fmaxf((rT + ct.x) - 2.0f * gg.x, 0.0f));
      d.y = sqrtf(fmaxf((rT + ct.y) - 2.0f * gg.y, 0.0f));
      d.z = sqrtf(fmaxf((rT + ct.z) - 2.0f * gg.z, 0.0f));
      d.w = sqrtf(fmaxf((rT + ct.w) - 2.0f * gg.w, 0.0f));
      *(float4*)&sBuf[j4] = d;
    }
    __syncthreads();

    const uint32_t fk0 = keys.k[2 * v], fk1 = keys.k[2 * v + 1];
    const uint32_t tbase = (uint32_t)i * 4096u;
    for (int k = tid; k < npos; k += 256) {
      const int j = plist[k];
      const uint32_t t32 = tbase + (uint32_t)j;
      uint32_t y0, y1, bits;
      if (i < 2048) { tf2x32(fk0, fk1, t32, t32 + 8388608u, &y0, &y1); bits = y0; }
      else          { tf2x32(fk0, fk1, t32 - 8388608u, t32, &y0, &y1); bits = y1; }
      const float u = __uint_as_float((bits >> 9) | 0x3F800000u) - 1.0f;
      int r = (int)(u * cntf);
      r = min(r, cm1);
      const int n = zlist[r];
      lossSum += fmaxf(sBuf[j] - sBuf[n] + 1.0f, 0.0f);
    }
    __syncthreads();   // before next view overwrites sBuf
  }

  // ---- block reduce ----
  #pragma unroll
  for (int off = 32; off; off >>= 1) lossSum += __shfl_down(lossSum, off);
  if (lane == 0) sLoss[wid] = lossSum;
  __syncthreads();
  if (tid == 0) {
    const double tot = (double)sLoss[0] + (double)sLoss[1] + (double)sLoss[2] + (double)sLoss[3];
    atomicAdd(lossAcc, tot);
    atomicAdd(posAcc, (unsigned long long)npos);
  }
}

__global__ void finalize_kernel(const double* __restrict__ lossAcc,
                                const unsigned long long* __restrict__ posAcc,
                                float* __restrict__ out) {
  if (threadIdx.x == 0 && blockIdx.x == 0) {
    out[0] = (float)(lossAcc[0] / (double)posAcc[0]);
  }
}

// ---------------- launch ----------------
extern "C" void kernel_launch(void* const* d_in, const int* in_sizes, int n_in,
                              void* d_out, int out_size, void* d_ws, size_t ws_size,
                              hipStream_t stream) {
  if (ws_size < WS_NEEDED) return;

  const float* Xs[3] = { (const float*)d_in[0], (const float*)d_in[1], (const float*)d_in[2] };
  char* ws = (char*)d_ws;
  __bf16* Xhi = (__bf16*)(ws + XHI_OFF);
  __bf16* Xlo = (__bf16*)(ws + XLO_OFF);
  float* rowT = (float*)(ws + RT_OFF);
  float* colT = (float*)(ws + CT_OFF);
  float* G  = (float*)(ws + G_OFF);
  double* lossAcc = (double*)(ws + ACC_OFF);
  unsigned long long* posAcc = (unsigned long long*)(ws + ACC_OFF + 8);
  float* out = (float*)d_out;

  hipMemsetAsync(ws + ACC_OFF, 0, 16, stream);

  for (int v = 0; v < 3; ++v)
    norm_kernel<<<NROW, 128, 0, stream>>>(Xs[v],
                                          Xhi + (size_t)v * NROW * NDIM,
                                          Xlo + (size_t)v * NROW * NDIM,
                                          rowT + v * NROW, colT + v * NROW);

  gemm_syrk_bf16<<<3 * 528, 256, 0, stream>>>(Xhi, Xlo, G);

  Keys keys;
  for (uint32_t v = 0; v < 3; ++v) {
    uint32_t y0, y1;
    tf2x32(0u, 42u, 0u, v, &y0, &y1);
    keys.k[2 * v] = y0; keys.k[2 * v + 1] = y1;
  }

  loss_kernel<<<NROW, 256, 0, stream>>>(G, rowT, colT, lossAcc, posAcc, keys);
  finalize_kernel<<<1, 1, 0, stream>>>(lossAcc, posAcc, out);
}